// Round 4
// baseline (410.113 us; speedup 1.0000x reference)
//
#include <hip/hip_runtime.h>
#include <hip/hip_bf16.h>
#include <math.h>

#define NN 50000
#define EE 640000
#define DD 128
#define NREL 8
#define NCLS 16
#define NBUCK (NREL * NN)              // 400000 (dst,rel) buckets, key = dst*8+rel
#define SCAN_NB ((NBUCK + 255) / 256)  // 1563

typedef __attribute__((ext_vector_type(8))) short short8;   // 8 bf16 = 4 VGPRs
typedef __attribute__((ext_vector_type(4))) float f32x4;    // MFMA acc

__device__ __forceinline__ float bf2f(ushort u) {
  return __uint_as_float(((unsigned)u) << 16);
}
__device__ __forceinline__ ushort f2b(float f) {  // RNE
  unsigned u = __float_as_uint(f);
  u += 0x7fff + ((u >> 16) & 1);
  return (ushort)(u >> 16);
}

// ---------- CSR build (key = dst*8 + rel) ----------

__global__ __launch_bounds__(256) void count_kernel(const int* __restrict__ ei,
                                                    const int* __restrict__ et,
                                                    int* __restrict__ cnt) {
  int t = blockIdx.x * 256 + threadIdx.x;
  if (t < EE) {
    int key = ei[EE + t] * NREL + et[t];
    atomicAdd(&cnt[key], 1);
  }
}

__global__ __launch_bounds__(256) void scan1_kernel(const int* __restrict__ cnt,
                                                    int* __restrict__ off,
                                                    int* __restrict__ bsum) {
  __shared__ int s[256];
  const int tid = threadIdx.x;
  const int i = blockIdx.x * 256 + tid;
  int v = (i < NBUCK) ? cnt[i] : 0;
  s[tid] = v;
  __syncthreads();
#pragma unroll
  for (int o = 1; o < 256; o <<= 1) {
    int t2 = (tid >= o) ? s[tid - o] : 0;
    __syncthreads();
    s[tid] += t2;
    __syncthreads();
  }
  if (i < NBUCK) off[i] = s[tid] - v;
  if (tid == 255) bsum[blockIdx.x] = s[255];
}

__global__ __launch_bounds__(256) void scan2_kernel(const int* __restrict__ bsum,
                                                    int* __restrict__ bpre) {
  __shared__ int s[256];
  __shared__ int carry;
  const int tid = threadIdx.x;
  if (tid == 0) carry = 0;
  __syncthreads();
  const int chunks = (SCAN_NB + 255) / 256;
  for (int c = 0; c < chunks; c++) {
    int idx = c * 256 + tid;
    int v = (idx < SCAN_NB) ? bsum[idx] : 0;
    s[tid] = v;
    __syncthreads();
#pragma unroll
    for (int o = 1; o < 256; o <<= 1) {
      int t2 = (tid >= o) ? s[tid - o] : 0;
      __syncthreads();
      s[tid] += t2;
      __syncthreads();
    }
    if (idx < SCAN_NB) bpre[idx] = carry + s[tid] - v;
    __syncthreads();
    if (tid == 255) carry += s[255];
    __syncthreads();
  }
}

__global__ __launch_bounds__(256) void scan3_kernel(int* __restrict__ off,
                                                    const int* __restrict__ bpre) {
  int i = blockIdx.x * 256 + threadIdx.x;
  if (i < NBUCK) off[i] += bpre[i >> 8];
  if (i == 0) off[NBUCK] = EE;
}

// rec = (src, raw edge weight); scale division happens in gathers (1/bucket_len)
__global__ __launch_bounds__(256) void bucket_kernel(const int* __restrict__ ei,
                                                     const int* __restrict__ et,
                                                     const float* __restrict__ ew,
                                                     int* __restrict__ cursor,
                                                     uint2* __restrict__ rec) {
  int e = blockIdx.x * 256 + threadIdx.x;
  if (e >= EE) return;
  int key = ei[EE + e] * NREL + et[e];
  int pos = atomicAdd(&cursor[key], 1);
  rec[pos] = make_uint2((unsigned)ei[e], __float_as_uint(ew[e]));
}

// ---------- packs ----------

__global__ __launch_bounds__(256) void pack_x_kernel(const float* __restrict__ x,
                                                     ushort* __restrict__ xb) {
  int t = blockIdx.x * 256 + threadIdx.x;
  if (t >= NN * DD / 4) return;
  float4 v = *(const float4*)&x[(size_t)t * 4];
  *(ushort4*)&xb[(size_t)t * 4] = make_ushort4(f2b(v.x), f2b(v.y), f2b(v.z), f2b(v.w));
}

// W1Tc[n*1024 + r*128 + k] = bf16(W1[r][k][n])   (n = out col, K-concat over r)
// W2T [j*128 + k]          = bf16(W2[j>>4][k][j&15])
__global__ __launch_bounds__(256) void pack_w_kernel(const float* __restrict__ W1,
                                                     const float* __restrict__ W2,
                                                     ushort* __restrict__ W1Tc,
                                                     ushort* __restrict__ W2T) {
  int t = blockIdx.x * 256 + threadIdx.x;
  if (t < NREL * DD * DD) {
    int n = t >> 10, r = (t >> 7) & 7, k = t & 127;
    W1Tc[t] = f2b(W1[r * 16384 + k * 128 + n]);
  } else if (t < NREL * DD * DD + DD * DD) {
    int t2 = t - NREL * DD * DD;
    int j = t2 >> 7, k = t2 & 127;
    W2T[t2] = f2b(W2[(j >> 4) * (DD * NCLS) + k * NCLS + (j & 15)]);
  }
}

// ---------- gather1: Agg[v][r*128+c] = bf16( sum_bucket (ew/cnt) * xb[src][c] ) ----------
// 1 node per block, 8 groups (one per relation) x 32 lanes x 4 cols.
__global__ __launch_bounds__(256) void gather1_kernel(const int* __restrict__ off,
                                                      const uint2* __restrict__ rec,
                                                      const ushort* __restrict__ xb,
                                                      ushort* __restrict__ Agg) {
  const int v = blockIdx.x;
  const int g = threadIdx.x >> 5;
  const int c4 = (threadIdx.x & 31) * 4;
  const int b = v * NREL + g;
  const int s = off[b], e = off[b + 1];
  const float inv = 1.0f / fmaxf((float)(e - s), 1.0f);
  float a0 = 0.f, a1 = 0.f, a2 = 0.f, a3 = 0.f;
  for (int i = s; i < e; i++) {
    uint2 q = rec[i];
    float sc = __uint_as_float(q.y) * inv;
    ushort4 h = *(const ushort4*)&xb[(size_t)q.x * DD + c4];
    a0 = fmaf(sc, bf2f(h.x), a0);
    a1 = fmaf(sc, bf2f(h.y), a1);
    a2 = fmaf(sc, bf2f(h.z), a2);
    a3 = fmaf(sc, bf2f(h.w), a3);
  }
  *(ushort4*)&Agg[(size_t)v * 1024 + g * DD + c4] =
      make_ushort4(f2b(a0), f2b(a1), f2b(a2), f2b(a3));
}

// ---------- gemm1: A2[NN x 128] = bf16(relu( Agg[NN x 1024] @ W1Tc^T )) ----------
// M-tile 64, K = 1024 in 8 chunks of 128; wave w owns cols [w*32, w*32+32).
__global__ __launch_bounds__(256) void gemm1_kernel(const ushort* __restrict__ Agg,
                                                    const ushort* __restrict__ Bt,
                                                    ushort* __restrict__ A2) {
  __shared__ ushort As[64 * 136];
  __shared__ ushort Bs[128 * 136];
  const int tid = threadIdx.x;
  const int m0 = blockIdx.x * 64;
  const int wave = tid >> 6, lane = tid & 63;
  const int lm = lane & 15, lkb = (lane >> 4) * 8;
  f32x4 acc[4][2];
#pragma unroll
  for (int m = 0; m < 4; m++)
#pragma unroll
    for (int j = 0; j < 2; j++) acc[m][j] = (f32x4){0.f, 0.f, 0.f, 0.f};

  for (int ch = 0; ch < 8; ch++) {
    uint4 va[4], vb[8];
#pragma unroll
    for (int i = 0; i < 4; i++) {
      int seg = tid + i * 256;           // 1024 segs: 64 rows x 16 col-chunks
      int row = seg >> 4, c8 = (seg & 15) * 8;
      int gr = m0 + row;
      va[i] = make_uint4(0u, 0u, 0u, 0u);
      if (gr < NN) va[i] = *(const uint4*)&Agg[(size_t)gr * 1024 + ch * 128 + c8];
    }
#pragma unroll
    for (int i = 0; i < 8; i++) {
      int seg = tid + i * 256;           // 2048 segs: 128 rows x 16 col-chunks
      int row = seg >> 4, c8 = (seg & 15) * 8;
      vb[i] = *(const uint4*)&Bt[(size_t)row * 1024 + ch * 128 + c8];
    }
    __syncthreads();  // previous chunk's compute done
#pragma unroll
    for (int i = 0; i < 4; i++) {
      int seg = tid + i * 256;
      int row = seg >> 4, c8 = (seg & 15) * 8;
      *(uint4*)&As[row * 136 + c8] = va[i];
    }
#pragma unroll
    for (int i = 0; i < 8; i++) {
      int seg = tid + i * 256;
      int row = seg >> 4, c8 = (seg & 15) * 8;
      *(uint4*)&Bs[row * 136 + c8] = vb[i];
    }
    __syncthreads();
#pragma unroll
    for (int k0 = 0; k0 < 128; k0 += 32) {
      short8 a[4];
#pragma unroll
      for (int m = 0; m < 4; m++)
        a[m] = *(const short8*)&As[(m * 16 + lm) * 136 + k0 + lkb];
#pragma unroll
      for (int j = 0; j < 2; j++) {
        short8 b = *(const short8*)&Bs[((wave * 2 + j) * 16 + lm) * 136 + k0 + lkb];
#pragma unroll
        for (int m = 0; m < 4; m++)
          acc[m][j] = __builtin_amdgcn_mfma_f32_16x16x32_bf16(a[m], b, acc[m][j], 0, 0, 0);
      }
    }
  }

  // epilogue: relu -> bf16 via LDS (As region), coalesced store
  __syncthreads();
  const int rquad = (lane >> 4) * 4;
#pragma unroll
  for (int m = 0; m < 4; m++)
#pragma unroll
    for (int j = 0; j < 2; j++)
#pragma unroll
      for (int i = 0; i < 4; i++)
        As[(m * 16 + rquad + i) * 136 + wave * 32 + j * 16 + lm] =
            f2b(fmaxf(acc[m][j][i], 0.f));
  __syncthreads();
#pragma unroll
  for (int i = 0; i < 4; i++) {
    int seg = tid + i * 256;
    int row = seg >> 4, c8 = (seg & 15) * 8;
    int gr = m0 + row;
    if (gr < NN) *(uint4*)&A2[(size_t)gr * DD + c8] = *(const uint4*)&As[row * 136 + c8];
  }
}

// ---------- gemm2: H2[NN x 128] = bf16( A2 @ W2T^T ), K = 128 ----------
__global__ __launch_bounds__(256) void gemm2_kernel(const ushort* __restrict__ A,
                                                    const ushort* __restrict__ Bt,
                                                    ushort* __restrict__ C) {
  __shared__ ushort As[128 * 136];
  __shared__ ushort Bs[128 * 136];
  const int tid = threadIdx.x;
  const int m0 = blockIdx.x * 128;
#pragma unroll
  for (int i = 0; i < 8; i++) {
    int seg = tid + i * 256;
    int row = seg >> 4, c8 = (seg & 15) * 8;
    uint4 va = make_uint4(0u, 0u, 0u, 0u);
    int gr = m0 + row;
    if (gr < NN) va = *(const uint4*)&A[(size_t)gr * DD + c8];
    *(uint4*)&As[row * 136 + c8] = va;
    *(uint4*)&Bs[row * 136 + c8] = *(const uint4*)&Bt[row * DD + c8];
  }
  __syncthreads();
  const int wave = tid >> 6, lane = tid & 63;
  const int lm = lane & 15, lkb = (lane >> 4) * 8;
  const int mbase = wave * 32;
  f32x4 acc[2][8];
#pragma unroll
  for (int t = 0; t < 2; t++)
#pragma unroll
    for (int n = 0; n < 8; n++) acc[t][n] = (f32x4){0.f, 0.f, 0.f, 0.f};
#pragma unroll
  for (int k0 = 0; k0 < 128; k0 += 32) {
    short8 a0 = *(const short8*)&As[(mbase + lm) * 136 + k0 + lkb];
    short8 a1 = *(const short8*)&As[(mbase + 16 + lm) * 136 + k0 + lkb];
#pragma unroll
    for (int n = 0; n < 8; n++) {
      short8 b = *(const short8*)&Bs[(n * 16 + lm) * 136 + k0 + lkb];
      acc[0][n] = __builtin_amdgcn_mfma_f32_16x16x32_bf16(a0, b, acc[0][n], 0, 0, 0);
      acc[1][n] = __builtin_amdgcn_mfma_f32_16x16x32_bf16(a1, b, acc[1][n], 0, 0, 0);
    }
  }
  __syncthreads();
  const int rquad = (lane >> 4) * 4;
#pragma unroll
  for (int t = 0; t < 2; t++)
#pragma unroll
    for (int i = 0; i < 4; i++) {
      int lrow = mbase + t * 16 + rquad + i;
#pragma unroll
      for (int n = 0; n < 8; n++)
        As[lrow * 136 + n * 16 + lm] = f2b(acc[t][n][i]);
    }
  __syncthreads();
#pragma unroll
  for (int i = 0; i < 8; i++) {
    int seg = tid + i * 256;
    int row = seg >> 4, c8 = (seg & 15) * 8;
    int gr = m0 + row;
    if (gr < NN) *(uint4*)&C[(size_t)gr * DD + c8] = *(const uint4*)&As[row * 136 + c8];
  }
}

// ---------- gather2 + log_softmax: block = 2 nodes x 8 rel-groups x 16 lanes ----------
__global__ __launch_bounds__(256) void gather2_kernel(const int* __restrict__ off,
                                                      const uint2* __restrict__ rec,
                                                      const ushort* __restrict__ H2,
                                                      float* __restrict__ out) {
  __shared__ float part[2][8][16];
  const int tid = threadIdx.x;
  const int nloc = tid >> 7;
  const int v = blockIdx.x * 2 + nloc;
  const int r = (tid >> 4) & 7;
  const int c = tid & 15;
  const int b = v * NREL + r;
  const int s = off[b], e = off[b + 1];
  const float inv = 1.0f / fmaxf((float)(e - s), 1.0f);
  float acc = 0.f;
  for (int i = s; i < e; i++) {
    uint2 q = rec[i];
    acc = fmaf(__uint_as_float(q.y) * inv,
               bf2f(H2[(size_t)q.x * DD + r * NCLS + c]), acc);
  }
  part[nloc][r][c] = acc;
  __syncthreads();
  if (r == 0) {
    float val = 0.f;
#pragma unroll
    for (int g = 0; g < 8; g++) val += part[nloc][g][c];
    float m = val;
#pragma unroll
    for (int mask = 8; mask >= 1; mask >>= 1) m = fmaxf(m, __shfl_xor(m, mask, 16));
    float ex = expf(val - m);
#pragma unroll
    for (int mask = 8; mask >= 1; mask >>= 1) ex += __shfl_xor(ex, mask, 16);
    out[(size_t)v * NCLS + c] = val - m - logf(ex);
  }
}

extern "C" void kernel_launch(void* const* d_in, const int* in_sizes, int n_in,
                              void* d_out, int out_size, void* d_ws, size_t ws_size,
                              hipStream_t stream) {
  const float* x  = (const float*)d_in[0];
  const int*   ei = (const int*)d_in[1];
  const int*   et = (const int*)d_in[2];
  const float* ew = (const float*)d_in[3];
  const float* W1 = (const float*)d_in[4];
  const float* W2 = (const float*)d_in[5];
  float* out = (float*)d_out;
  float* ws = (float*)d_ws;

  // workspace layout (float-unit offsets; ~151 MB)
  int*    cnt    = (int*)ws;                   // 400000
  int*    off    = (int*)(ws + 400000);        // 400001
  int*    bsum   = (int*)(ws + 800004);        // 1563
  int*    bpre   = (int*)(ws + 801568);        // 1563
  int*    cursor = (int*)(ws + 803132);        // 400000
  uint2*  rec    = (uint2*)(ws + 1203132);     // 640000 uint2
  ushort* xb     = (ushort*)(ws + 2483132);    // NN*DD bf16
  ushort* W1Tc   = (ushort*)(ws + 5683132);    // 128*1024 bf16 (K-concat, col-major-T)
  ushort* W2T    = (ushort*)(ws + 5748668);    // 128*128 bf16
  ushort* Agg    = (ushort*)(ws + 5756860);    // NN*1024 bf16 (102.4 MB)
  ushort* A2     = (ushort*)(ws + 31356860);   // NN*DD bf16
  ushort* H2     = (ushort*)(ws + 34556860);   // NN*DD bf16

  hipMemsetAsync(cnt, 0, (size_t)NBUCK * sizeof(int), stream);

  count_kernel<<<(EE + 255) / 256, 256, 0, stream>>>(ei, et, cnt);
  scan1_kernel<<<SCAN_NB, 256, 0, stream>>>(cnt, off, bsum);
  scan2_kernel<<<1, 256, 0, stream>>>(bsum, bpre);
  scan3_kernel<<<SCAN_NB, 256, 0, stream>>>(off, bpre);
  hipMemcpyAsync(cursor, off, (size_t)NBUCK * sizeof(int), hipMemcpyDeviceToDevice, stream);
  bucket_kernel<<<(EE + 255) / 256, 256, 0, stream>>>(ei, et, ew, cursor, rec);

  pack_x_kernel<<<(NN * DD / 4 + 255) / 256, 256, 0, stream>>>(x, xb);
  pack_w_kernel<<<(NREL * DD * DD + DD * DD + 255) / 256, 256, 0, stream>>>(W1, W2, W1Tc, W2T);

  gather1_kernel<<<NN, 256, 0, stream>>>(off, rec, xb, Agg);
  gemm1_kernel<<<(NN + 63) / 64, 256, 0, stream>>>(Agg, W1Tc, A2);
  gemm2_kernel<<<(NN + 127) / 128, 256, 0, stream>>>(A2, W2T, H2);
  gather2_kernel<<<NN / 2, 256, 0, stream>>>(off, rec, H2, out);
}

// Round 5
// 309.642 us; speedup vs baseline: 1.3245x; 1.3245x over previous
//
#include <hip/hip_runtime.h>
#include <hip/hip_bf16.h>
#include <math.h>

#define NN 50000
#define EE 640000
#define DD 128
#define NREL 8
#define NCLS 16
#define NBUCK (NREL * NN)              // 400000 (dst,rel) buckets, key = dst*8+rel
#define SCAN_NB ((NBUCK + 255) / 256)  // 1563

typedef __attribute__((ext_vector_type(8))) short short8;   // 8 bf16 = 4 VGPRs
typedef __attribute__((ext_vector_type(4))) float f32x4;    // MFMA acc

__device__ __forceinline__ float bf2f(ushort u) {
  return __uint_as_float(((unsigned)u) << 16);
}
__device__ __forceinline__ ushort f2b(float f) {  // RNE
  unsigned u = __float_as_uint(f);
  u += 0x7fff + ((u >> 16) & 1);
  return (ushort)(u >> 16);
}

// ---------- CSR build (key = dst*8 + rel) ----------

__global__ __launch_bounds__(256) void count_kernel(const int* __restrict__ ei,
                                                    const int* __restrict__ et,
                                                    int* __restrict__ cnt) {
  int t = blockIdx.x * 256 + threadIdx.x;
  if (t < EE) {
    int key = ei[EE + t] * NREL + et[t];
    atomicAdd(&cnt[key], 1);
  }
}

__global__ __launch_bounds__(256) void scan1_kernel(const int* __restrict__ cnt,
                                                    int* __restrict__ off,
                                                    int* __restrict__ bsum) {
  __shared__ int s[256];
  const int tid = threadIdx.x;
  const int i = blockIdx.x * 256 + tid;
  int v = (i < NBUCK) ? cnt[i] : 0;
  s[tid] = v;
  __syncthreads();
#pragma unroll
  for (int o = 1; o < 256; o <<= 1) {
    int t2 = (tid >= o) ? s[tid - o] : 0;
    __syncthreads();
    s[tid] += t2;
    __syncthreads();
  }
  if (i < NBUCK) off[i] = s[tid] - v;
  if (tid == 255) bsum[blockIdx.x] = s[255];
}

__global__ __launch_bounds__(256) void scan2_kernel(const int* __restrict__ bsum,
                                                    int* __restrict__ bpre) {
  __shared__ int s[256];
  __shared__ int carry;
  const int tid = threadIdx.x;
  if (tid == 0) carry = 0;
  __syncthreads();
  const int chunks = (SCAN_NB + 255) / 256;
  for (int c = 0; c < chunks; c++) {
    int idx = c * 256 + tid;
    int v = (idx < SCAN_NB) ? bsum[idx] : 0;
    s[tid] = v;
    __syncthreads();
#pragma unroll
    for (int o = 1; o < 256; o <<= 1) {
      int t2 = (tid >= o) ? s[tid - o] : 0;
      __syncthreads();
      s[tid] += t2;
      __syncthreads();
    }
    if (idx < SCAN_NB) bpre[idx] = carry + s[tid] - v;
    __syncthreads();
    if (tid == 255) carry += s[255];
    __syncthreads();
  }
}

__global__ __launch_bounds__(256) void scan3_kernel(int* __restrict__ off,
                                                    const int* __restrict__ bpre) {
  int i = blockIdx.x * 256 + threadIdx.x;
  if (i < NBUCK) off[i] += bpre[i >> 8];
  if (i == 0) off[NBUCK] = EE;
}

// rec = (src, raw edge weight); scale division happens at use (1/bucket_len)
__global__ __launch_bounds__(256) void bucket_kernel(const int* __restrict__ ei,
                                                     const int* __restrict__ et,
                                                     const float* __restrict__ ew,
                                                     int* __restrict__ cursor,
                                                     uint2* __restrict__ rec) {
  int e = blockIdx.x * 256 + threadIdx.x;
  if (e >= EE) return;
  int key = ei[EE + e] * NREL + et[e];
  int pos = atomicAdd(&cursor[key], 1);
  rec[pos] = make_uint2((unsigned)ei[e], __float_as_uint(ew[e]));
}

// ---------- packs ----------

__global__ __launch_bounds__(256) void pack_x_kernel(const float* __restrict__ x,
                                                     ushort* __restrict__ xb) {
  int t = blockIdx.x * 256 + threadIdx.x;
  if (t >= NN * DD / 4) return;
  float4 v = *(const float4*)&x[(size_t)t * 4];
  *(ushort4*)&xb[(size_t)t * 4] = make_ushort4(f2b(v.x), f2b(v.y), f2b(v.z), f2b(v.w));
}

// W1Tc[n*1024 + r*128 + k] = bf16(W1[r][k][n])   (n = out col, K-concat over r)
// W2T [j*128 + k]          = bf16(W2[j>>4][k][j&15])
__global__ __launch_bounds__(256) void pack_w_kernel(const float* __restrict__ W1,
                                                     const float* __restrict__ W2,
                                                     ushort* __restrict__ W1Tc,
                                                     ushort* __restrict__ W2T) {
  int t = blockIdx.x * 256 + threadIdx.x;
  if (t < NREL * DD * DD) {
    int n = t >> 10, r = (t >> 7) & 7, k = t & 127;
    W1Tc[t] = f2b(W1[r * 16384 + k * 128 + n]);
  } else if (t < NREL * DD * DD + DD * DD) {
    int t2 = t - NREL * DD * DD;
    int j = t2 >> 7, k = t2 & 127;
    W2T[t2] = f2b(W2[(j >> 4) * (DD * NCLS) + k * NCLS + (j & 15)]);
  }
}

// ---------- fused layer 1: gather (dst,rel)-chunk into LDS + MFMA ----------
// A2[v][:] = bf16(relu( sum_r Aggchunk(v,r) @ W1[r] )), Agg never hits HBM.
// Block = 64 nodes. Per chunk r: 4 threads/node x 32 cols gather -> As;
// Bs = W1Tc slice [128 out-cols][128 k]; 4 waves each own 32 out-cols.
__global__ __launch_bounds__(256) void fused1_kernel(const int* __restrict__ off,
                                                     const uint2* __restrict__ rec,
                                                     const ushort* __restrict__ xb,
                                                     const ushort* __restrict__ Bt,
                                                     ushort* __restrict__ A2) {
  __shared__ ushort As[64 * 136];
  __shared__ ushort Bs[128 * 136];
  const int tid = threadIdx.x;
  const int m0 = blockIdx.x * 64;
  const int wave = tid >> 6, lane = tid & 63;
  const int lm = lane & 15, lkb = (lane >> 4) * 8;
  const int gn = tid >> 2;          // gather: node 0..63
  const int gc = (tid & 3) * 32;    // gather: col base
  const int v = m0 + gn;

  f32x4 acc[4][2];
#pragma unroll
  for (int m = 0; m < 4; m++)
#pragma unroll
    for (int j = 0; j < 2; j++) acc[m][j] = (f32x4){0.f, 0.f, 0.f, 0.f};

  for (int r = 0; r < NREL; r++) {
    __syncthreads();  // previous chunk's As/Bs reads complete
    // stage B chunk (W1Tc slice for relation r)
#pragma unroll
    for (int i = 0; i < 8; i++) {
      int seg = tid + i * 256;
      int row = seg >> 4, c8 = (seg & 15) * 8;
      *(uint4*)&Bs[row * 136 + c8] =
          *(const uint4*)&Bt[(size_t)row * 1024 + r * 128 + c8];
    }
    // gather chunk: fp32 accumulate 32 cols of node v, relation r
    float g[32];
#pragma unroll
    for (int j = 0; j < 32; j++) g[j] = 0.f;
    if (v < NN) {
      int b = v * NREL + r;
      int s = off[b], e = off[b + 1];
      float inv = 1.0f / fmaxf((float)(e - s), 1.0f);
      for (int i = s; i < e; i++) {
        uint2 q = rec[i];
        float sc = __uint_as_float(q.y) * inv;
        const ushort* xr = &xb[(size_t)q.x * DD + gc];
#pragma unroll
        for (int jj = 0; jj < 4; jj++) {
          uint4 h = *(const uint4*)&xr[jj * 8];
          float* gg = &g[jj * 8];
          gg[0] = fmaf(sc, __uint_as_float(h.x << 16), gg[0]);
          gg[1] = fmaf(sc, __uint_as_float(h.x & 0xffff0000u), gg[1]);
          gg[2] = fmaf(sc, __uint_as_float(h.y << 16), gg[2]);
          gg[3] = fmaf(sc, __uint_as_float(h.y & 0xffff0000u), gg[3]);
          gg[4] = fmaf(sc, __uint_as_float(h.z << 16), gg[4]);
          gg[5] = fmaf(sc, __uint_as_float(h.z & 0xffff0000u), gg[5]);
          gg[6] = fmaf(sc, __uint_as_float(h.w << 16), gg[6]);
          gg[7] = fmaf(sc, __uint_as_float(h.w & 0xffff0000u), gg[7]);
        }
      }
    }
#pragma unroll
    for (int jj = 0; jj < 4; jj++) {
      uint4 u;
      u.x = (unsigned)f2b(g[jj * 8 + 0]) | ((unsigned)f2b(g[jj * 8 + 1]) << 16);
      u.y = (unsigned)f2b(g[jj * 8 + 2]) | ((unsigned)f2b(g[jj * 8 + 3]) << 16);
      u.z = (unsigned)f2b(g[jj * 8 + 4]) | ((unsigned)f2b(g[jj * 8 + 5]) << 16);
      u.w = (unsigned)f2b(g[jj * 8 + 6]) | ((unsigned)f2b(g[jj * 8 + 7]) << 16);
      *(uint4*)&As[gn * 136 + gc + jj * 8] = u;
    }
    __syncthreads();
    // MFMA on this chunk
#pragma unroll
    for (int k0 = 0; k0 < 128; k0 += 32) {
      short8 a[4];
#pragma unroll
      for (int m = 0; m < 4; m++)
        a[m] = *(const short8*)&As[(m * 16 + lm) * 136 + k0 + lkb];
#pragma unroll
      for (int j = 0; j < 2; j++) {
        short8 b = *(const short8*)&Bs[((wave * 2 + j) * 16 + lm) * 136 + k0 + lkb];
#pragma unroll
        for (int m = 0; m < 4; m++)
          acc[m][j] = __builtin_amdgcn_mfma_f32_16x16x32_bf16(a[m], b, acc[m][j], 0, 0, 0);
      }
    }
  }

  // epilogue: relu -> bf16 via LDS (As region), coalesced store
  __syncthreads();
  const int rquad = (lane >> 4) * 4;
#pragma unroll
  for (int m = 0; m < 4; m++)
#pragma unroll
    for (int j = 0; j < 2; j++)
#pragma unroll
      for (int i = 0; i < 4; i++)
        As[(m * 16 + rquad + i) * 136 + wave * 32 + j * 16 + lm] =
            f2b(fmaxf(acc[m][j][i], 0.f));
  __syncthreads();
#pragma unroll
  for (int i = 0; i < 4; i++) {
    int seg = tid + i * 256;
    int row = seg >> 4, c8 = (seg & 15) * 8;
    int gr = m0 + row;
    if (gr < NN) *(uint4*)&A2[(size_t)gr * DD + c8] = *(const uint4*)&As[row * 136 + c8];
  }
}

// ---------- gemm2: H2[NN x 128] = bf16( A2 @ W2T^T ), K = 128 ----------
__global__ __launch_bounds__(256) void gemm2_kernel(const ushort* __restrict__ A,
                                                    const ushort* __restrict__ Bt,
                                                    ushort* __restrict__ C) {
  __shared__ ushort As[128 * 136];
  __shared__ ushort Bs[128 * 136];
  const int tid = threadIdx.x;
  const int m0 = blockIdx.x * 128;
#pragma unroll
  for (int i = 0; i < 8; i++) {
    int seg = tid + i * 256;
    int row = seg >> 4, c8 = (seg & 15) * 8;
    uint4 va = make_uint4(0u, 0u, 0u, 0u);
    int gr = m0 + row;
    if (gr < NN) va = *(const uint4*)&A[(size_t)gr * DD + c8];
    *(uint4*)&As[row * 136 + c8] = va;
    *(uint4*)&Bs[row * 136 + c8] = *(const uint4*)&Bt[row * DD + c8];
  }
  __syncthreads();
  const int wave = tid >> 6, lane = tid & 63;
  const int lm = lane & 15, lkb = (lane >> 4) * 8;
  const int mbase = wave * 32;
  f32x4 acc[2][8];
#pragma unroll
  for (int t = 0; t < 2; t++)
#pragma unroll
    for (int n = 0; n < 8; n++) acc[t][n] = (f32x4){0.f, 0.f, 0.f, 0.f};
#pragma unroll
  for (int k0 = 0; k0 < 128; k0 += 32) {
    short8 a0 = *(const short8*)&As[(mbase + lm) * 136 + k0 + lkb];
    short8 a1 = *(const short8*)&As[(mbase + 16 + lm) * 136 + k0 + lkb];
#pragma unroll
    for (int n = 0; n < 8; n++) {
      short8 b = *(const short8*)&Bs[(n * 16 + lm) * 136 + k0 + lkb];
      acc[0][n] = __builtin_amdgcn_mfma_f32_16x16x32_bf16(a0, b, acc[0][n], 0, 0, 0);
      acc[1][n] = __builtin_amdgcn_mfma_f32_16x16x32_bf16(a1, b, acc[1][n], 0, 0, 0);
    }
  }
  __syncthreads();
  const int rquad = (lane >> 4) * 4;
#pragma unroll
  for (int t = 0; t < 2; t++)
#pragma unroll
    for (int i = 0; i < 4; i++) {
      int lrow = mbase + t * 16 + rquad + i;
#pragma unroll
      for (int n = 0; n < 8; n++)
        As[lrow * 136 + n * 16 + lm] = f2b(acc[t][n][i]);
    }
  __syncthreads();
#pragma unroll
  for (int i = 0; i < 8; i++) {
    int seg = tid + i * 256;
    int row = seg >> 4, c8 = (seg & 15) * 8;
    int gr = m0 + row;
    if (gr < NN) *(uint4*)&C[(size_t)gr * DD + c8] = *(const uint4*)&As[row * 136 + c8];
  }
}

// ---------- gather2 + log_softmax: block = 2 nodes x 8 rel-groups x 16 lanes ----------
__global__ __launch_bounds__(256) void gather2_kernel(const int* __restrict__ off,
                                                      const uint2* __restrict__ rec,
                                                      const ushort* __restrict__ H2,
                                                      float* __restrict__ out) {
  __shared__ float part[2][8][16];
  const int tid = threadIdx.x;
  const int nloc = tid >> 7;
  const int v = blockIdx.x * 2 + nloc;
  const int r = (tid >> 4) & 7;
  const int c = tid & 15;
  const int b = v * NREL + r;
  const int s = off[b], e = off[b + 1];
  const float inv = 1.0f / fmaxf((float)(e - s), 1.0f);
  float acc = 0.f;
  for (int i = s; i < e; i++) {
    uint2 q = rec[i];
    acc = fmaf(__uint_as_float(q.y) * inv,
               bf2f(H2[(size_t)q.x * DD + r * NCLS + c]), acc);
  }
  part[nloc][r][c] = acc;
  __syncthreads();
  if (r == 0) {
    float val = 0.f;
#pragma unroll
    for (int g = 0; g < 8; g++) val += part[nloc][g][c];
    float m = val;
#pragma unroll
    for (int mask = 8; mask >= 1; mask >>= 1) m = fmaxf(m, __shfl_xor(m, mask, 16));
    float ex = expf(val - m);
#pragma unroll
    for (int mask = 8; mask >= 1; mask >>= 1) ex += __shfl_xor(ex, mask, 16);
    out[(size_t)v * NCLS + c] = val - m - logf(ex);
  }
}

extern "C" void kernel_launch(void* const* d_in, const int* in_sizes, int n_in,
                              void* d_out, int out_size, void* d_ws, size_t ws_size,
                              hipStream_t stream) {
  const float* x  = (const float*)d_in[0];
  const int*   ei = (const int*)d_in[1];
  const int*   et = (const int*)d_in[2];
  const float* ew = (const float*)d_in[3];
  const float* W1 = (const float*)d_in[4];
  const float* W2 = (const float*)d_in[5];
  float* out = (float*)d_out;
  float* ws = (float*)d_ws;

  // workspace layout (float-unit offsets; ~49 MB)
  int*    cnt    = (int*)ws;                   // 400000
  int*    off    = (int*)(ws + 400000);        // 400001
  int*    bsum   = (int*)(ws + 800004);        // 1563
  int*    bpre   = (int*)(ws + 801568);        // 1563
  int*    cursor = (int*)(ws + 803132);        // 400000
  uint2*  rec    = (uint2*)(ws + 1203132);     // 640000 uint2
  ushort* xb     = (ushort*)(ws + 2483132);    // NN*DD bf16
  ushort* W1Tc   = (ushort*)(ws + 5683132);    // 128*1024 bf16 (K-concat, col-major-T)
  ushort* W2T    = (ushort*)(ws + 5748668);    // 128*128 bf16
  ushort* A2     = (ushort*)(ws + 5756860);    // NN*DD bf16
  ushort* H2     = (ushort*)(ws + 8956860);    // NN*DD bf16

  hipMemsetAsync(cnt, 0, (size_t)NBUCK * sizeof(int), stream);

  count_kernel<<<(EE + 255) / 256, 256, 0, stream>>>(ei, et, cnt);
  scan1_kernel<<<SCAN_NB, 256, 0, stream>>>(cnt, off, bsum);
  scan2_kernel<<<1, 256, 0, stream>>>(bsum, bpre);
  scan3_kernel<<<SCAN_NB, 256, 0, stream>>>(off, bpre);
  hipMemcpyAsync(cursor, off, (size_t)NBUCK * sizeof(int), hipMemcpyDeviceToDevice, stream);
  bucket_kernel<<<(EE + 255) / 256, 256, 0, stream>>>(ei, et, ew, cursor, rec);

  pack_x_kernel<<<(NN * DD / 4 + 255) / 256, 256, 0, stream>>>(x, xb);
  pack_w_kernel<<<(NREL * DD * DD + DD * DD + 255) / 256, 256, 0, stream>>>(W1, W2, W1Tc, W2T);

  fused1_kernel<<<(NN + 63) / 64, 256, 0, stream>>>(off, rec, xb, W1Tc, A2);
  gemm2_kernel<<<(NN + 127) / 128, 256, 0, stream>>>(A2, W2T, H2);
  gather2_kernel<<<NN / 2, 256, 0, stream>>>(off, rec, H2, out);
}